// Round 12
// baseline (5792.686 us; speedup 1.0000x reference)
//
#include <hip/hip_runtime.h>
#include <math.h>

#define B_ 16
#define T_ 64
#define N_ 512
#define H_ 128
#define P_ 12
#define NH 65536  // N_*H_

// ---------------------------------------------------------------------------
// Lx[b,t,m] = sum_n L[m,n] * x[b,t,n]   (L symmetric)
// ---------------------------------------------------------------------------
__global__ __launch_bounds__(512) void lx_kernel(const float* __restrict__ x,
                                                 const float* __restrict__ L,
                                                 float* __restrict__ Lx) {
    __shared__ __align__(16) float xs[2][N_];
    const int r0 = blockIdx.x * 2;
    const int tid = threadIdx.x;
    for (int j = 0; j < 2; ++j)
        xs[j][tid] = x[(size_t)(r0 + j) * N_ + tid];
    __syncthreads();
    float a0 = 0.f, a1 = 0.f;
    const int m = tid;
#pragma unroll 8
    for (int n = 0; n < N_; ++n) {
        float lv = L[(size_t)n * N_ + m];
        a0 += xs[0][n] * lv;
        a1 += xs[1][n] * lv;
    }
    Lx[(size_t)(r0 + 0) * N_ + m] = a0;
    Lx[(size_t)(r0 + 1) * N_ + m] = a1;
}

#define FMA4(dst, a, hv)                                                      \
    dst[0] += (a) * (hv).x; dst[1] += (a) * (hv).y;                           \
    dst[2] += (a) * (hv).z; dst[3] += (a) * (hv).w;

// ===========================================================================
// gc1z — R22: R12's PROVEN gc2a body verbatim (phase-1-only + Z dump), with
// Hprev as input.  Z = L @ Hprev -> written into hn (dead H(t-2) buffer).
// Rationale: cross-round audit shows the small GEMMs run ~4x faster as
// standalone 256-thread kernels (R13 gc2b ~6.5us, R15 y_kernel ~8us) than
// as phases appended inside the 512-thread gc1y (~33us for the same work,
// invariant under occupancy/latency/port/conflict fixes R15-R21).  So:
// strip gc1y back to phase-1-only and move ru+Y into a gc2b-style kernel.
// ===========================================================================
__global__ __launch_bounds__(512) void gc1z_kernel(
    const float* __restrict__ L, const float* __restrict__ Hprev,
    float* __restrict__ Z) {
    __shared__ __align__(16) float Ht[2][32][H_];   // 32768 B
    __shared__ __align__(16) float Lt[2][32][20];   // 5120 B
    __shared__ __align__(16) float Zb[16][H_];      // 8192 B

    const int tid = threadIdx.x;
    const int b = blockIdx.x & 15;
    const int m0 = (blockIdx.x >> 4) * 16;
    const float* __restrict__ Hb = Hprev + (size_t)b * NH;

    const int hrow = tid >> 5, hcol = (tid & 31) * 4;
    const int lm = tid >> 5, lk = tid & 31;

    {
        *(float4*)&Ht[0][hrow][hcol] = *(const float4*)&Hb[(size_t)hrow * H_ + hcol];
        *(float4*)&Ht[0][hrow + 16][hcol] =
            *(const float4*)&Hb[(size_t)(hrow + 16) * H_ + hcol];
        Lt[0][lk][lm] = L[(size_t)(m0 + lm) * N_ + lk];
    }
    __syncthreads();

    const int g = tid >> 6;
    const int l = tid & 63;
    const int ty = l >> 4;
    const int tx = l & 15;
    const int ma0 = ty * 4;
    const int ca0 = tx * 4, cb0 = 64 + tx * 4;

    float acc[4][2][4] = {};

    for (int kc = 0; kc < 16; ++kc) {
        const int bi = kc & 1, bj = bi ^ 1;
        float4 p0, p1;
        float pl;
        if (kc < 15) {
            const size_t kb = (size_t)(kc + 1) * 32;
            p0 = *(const float4*)&Hb[(kb + hrow) * H_ + hcol];
            p1 = *(const float4*)&Hb[(kb + hrow + 16) * H_ + hcol];
            pl = L[(size_t)(m0 + lm) * N_ + kb + lk];
        }
#pragma unroll
        for (int kk = 0; kk < 4; ++kk) {
            const int k = g * 4 + kk;
            const float4 la = *(const float4*)&Lt[bi][k][ma0];
            const float4 h0 = *(const float4*)&Ht[bi][k][ca0];
            const float4 h1 = *(const float4*)&Ht[bi][k][cb0];
            FMA4(acc[0][0], la.x, h0) FMA4(acc[0][1], la.x, h1)
            FMA4(acc[1][0], la.y, h0) FMA4(acc[1][1], la.y, h1)
            FMA4(acc[2][0], la.z, h0) FMA4(acc[2][1], la.z, h1)
            FMA4(acc[3][0], la.w, h0) FMA4(acc[3][1], la.w, h1)
        }
        if (kc < 15) {
            *(float4*)&Ht[bj][hrow][hcol] = p0;
            *(float4*)&Ht[bj][hrow + 16][hcol] = p1;
            Lt[bj][lk][lm] = pl;
        }
        __syncthreads();
    }

    for (int r = 0; r < 8; ++r) {
        if (g == r) {
#pragma unroll
            for (int i = 0; i < 4; ++i) {
#pragma unroll
                for (int v = 0; v < 2; ++v) {
                    const int c = v ? cb0 : ca0;
                    float4* zp = (float4*)&Zb[ma0 + i][c];
                    if (r == 0) {
                        *zp = make_float4(acc[i][v][0], acc[i][v][1],
                                          acc[i][v][2], acc[i][v][3]);
                    } else {
                        float4 z = *zp;
                        *zp = make_float4(z.x + acc[i][v][0], z.y + acc[i][v][1],
                                          z.z + acc[i][v][2], z.w + acc[i][v][3]);
                    }
                }
            }
        }
        __syncthreads();
    }

    {
        const int zr = tid >> 5, zc = (tid & 31) * 4;
        *(float4*)&Z[((size_t)b * NH) + (size_t)(m0 + zr) * H_ + zc] =
            *(const float4*)&Zb[zr][zc];
    }
}

// ===========================================================================
// ruy — R22: gc2b-skeleton (PROVEN fast standalone: R13 ~6.5us, R15 ~8us).
// 1024 blocks x 256 threads; block = (b, mt), mt 0..63 -> Z rows m0..m0+7.
// GEMM1: v[8] = Zs @ W1[1:]  (Wt flat-copy staging, unroll-1 ck loop);
// epilogue v += lx*W1[0] + b1; s = sigmoid(v).
// mt<32 (r-half): Rs = s * Hprev (LDS), then Y rows 2m0..2m0+15 = Rs@W2[1:].
// mt>=32: write u.  LDS 28,672 B.  Tripwires: VGPR>100 / dur>=25us.
// ===========================================================================
__global__ __launch_bounds__(256) void ruy_kernel(
    const float* __restrict__ Z, const float* __restrict__ Hprev,
    const float* __restrict__ Lx, const float* __restrict__ W1,
    const float* __restrict__ b1, const float* __restrict__ W2,
    float* __restrict__ Y, float* __restrict__ u, int t) {
    __shared__ __align__(16) float Zs[8][H_];     //  4096 B
    __shared__ __align__(16) float Wt[16][256];   // 16384 B
    __shared__ __align__(16) float Rs[16][H_];    //  8192 B -> 28672 B

    const int tid = threadIdx.x;
    const int b = blockIdx.x & 15;                 // XCD-locality decode
    const int mt = blockIdx.x >> 4;                // 0..63
    const int m0 = mt * 8;
    const int row = tid >> 5;                      // 0..7
    const int n = m0 + row;                        // this thread's Z row
    const int o0 = (tid & 31) * 8;                 // 0..248

    {
        const int c4 = (tid & 31) * 4;
        *(float4*)&Zs[row][c4] =
            *(const float4*)&Z[(size_t)b * NH + (size_t)n * H_ + c4];
    }

    float v[8] = {};
#pragma unroll 1
    for (int ck = 0; ck < 8; ++ck) {
        __syncthreads();   // ck=0: Zs visible; ck>0: protect Wt overwrite
        {   // stage W1 rows 1+16ck..16+16ck (contiguous 4096 floats), flat copy
            const float4* src = (const float4*)&W1[(size_t)(1 + ck * 16) * 256];
            float4* dst = (float4*)&Wt[0][0];
            dst[tid] = src[tid];
            dst[tid + 256] = src[tid + 256];
            dst[tid + 512] = src[tid + 512];
            dst[tid + 768] = src[tid + 768];
        }
        __syncthreads();
#pragma unroll
        for (int kk = 0; kk < 16; ++kk) {
            const float zk = Zs[row][ck * 16 + kk];
            const float4 wa = *(const float4*)&Wt[kk][o0];
            const float4 wb = *(const float4*)&Wt[kk][o0 + 4];
            v[0] += zk * wa.x; v[1] += zk * wa.y;
            v[2] += zk * wa.z; v[3] += zk * wa.w;
            v[4] += zk * wb.x; v[5] += zk * wb.y;
            v[6] += zk * wb.z; v[7] += zk * wb.w;
        }
    }
    __syncthreads();   // last Wt reads done before any Y-phase overwrite

    const float lx = Lx[((size_t)b * T_ + t) * N_ + n];
    float s[8];
#pragma unroll
    for (int j = 0; j < 8; ++j) {
        const float vv = v[j] + lx * W1[o0 + j] + b1[o0 + j];
        s[j] = 1.f / (1.f + expf(-vv));
    }

    if (mt < 32) {
        // r-half: Rs = s * Hprev  (H-linear offset n*256 + o0 == H-layout)
        const float* __restrict__ Hb = Hprev + (size_t)b * NH;
        const int fl = n * 256 + o0;
        const float4 h0 = *(const float4*)&Hb[fl];
        const float4 h1 = *(const float4*)&Hb[fl + 4];
        const int rr = 2 * row + (o0 >> 7);
        const int rc = o0 & 127;
        *(float4*)&Rs[rr][rc] =
            make_float4(s[0] * h0.x, s[1] * h0.y, s[2] * h0.z, s[3] * h0.w);
        *(float4*)&Rs[rr][rc + 4] =
            make_float4(s[4] * h1.x, s[5] * h1.y, s[6] * h1.z, s[7] * h1.w);
        __syncthreads();

        // Y phase: Y rows 2m0..2m0+15 = Rs @ W2[1:]
        const int yrow = tid >> 4;        // 0..15
        const int yo = (tid & 15) * 8;    // 0..120
        float a3[8] = {};
#pragma unroll 1
        for (int ck = 0; ck < 8; ++ck) {
            {   // stage W2 rows 1+16ck..16+16ck (2048 floats), flat copy
                const float4* src = (const float4*)&W2[(size_t)(1 + ck * 16) * H_];
                float4* dst = (float4*)&Wt[0][0];
                dst[tid] = src[tid];
                dst[tid + 256] = src[tid + 256];
            }
            __syncthreads();
#pragma unroll
            for (int kk = 0; kk < 16; ++kk) {
                const float rk = Rs[yrow][ck * 16 + kk];
                const float* wrow = &Wt[0][0] + kk * H_;
                const float4 wa = *(const float4*)&wrow[yo];
                const float4 wb = *(const float4*)&wrow[yo + 4];
                a3[0] += rk * wa.x; a3[1] += rk * wa.y;
                a3[2] += rk * wa.z; a3[3] += rk * wa.w;
                a3[4] += rk * wb.x; a3[5] += rk * wb.y;
                a3[6] += rk * wb.z; a3[7] += rk * wb.w;
            }
            __syncthreads();
        }
        float* __restrict__ Yb = Y + (size_t)b * NH;
        const size_t yoff = (size_t)(2 * m0 + yrow) * H_ + yo;
        *(float4*)&Yb[yoff] = make_float4(a3[0], a3[1], a3[2], a3[3]);
        *(float4*)&Yb[yoff + 4] = make_float4(a3[4], a3[5], a3[6], a3[7]);
    } else {
        // u-half: flat (n-256)*256+o0 == H-layout linear
        float* __restrict__ uB = u + (size_t)b * NH;
        const int fl = (n - 256) * 256 + o0;
        *(float4*)&uB[fl] = make_float4(s[0], s[1], s[2], s[3]);
        *(float4*)&uB[fl + 4] = make_float4(s[4], s[5], s[6], s[7]);
    }
}

// ===========================================================================
// gcz_kernel — R18 version VERBATIM (passed, ~13us): (L@Y) + gate epilogue.
// LDS 37,888 B.  DO NOT PERTURB.
// ===========================================================================
__global__ __launch_bounds__(512) void gcz_kernel(
    const float* __restrict__ L, const float* __restrict__ Y,
    const float* __restrict__ Hprev, const float* __restrict__ u,
    const float* __restrict__ Lx, const float* __restrict__ W2,
    const float* __restrict__ b2, const float* __restrict__ aw1,
    const float* __restrict__ ab1, float* __restrict__ Hnew,
    float* __restrict__ hs1, int t) {
    __shared__ __align__(16) union Buf {
        float Ht[2][32][H_];                              // 32768 B
        struct { float R[32][H_]; float Zb[16][H_]; } s;  // R unused here
    } bb;
    __shared__ __align__(16) float Lt[2][32][20];         // 5120 B

    const int tid = threadIdx.x;
    const int b = blockIdx.x & 15;
    const int m0 = (blockIdx.x >> 4) * 16;
    const float* __restrict__ Yb = Y + (size_t)b * NH;

    const int hrow = tid >> 5, hcol = (tid & 31) * 4;
    const int lm = tid >> 5, lk = tid & 31;

    {
        *(float4*)&bb.Ht[0][hrow][hcol] =
            *(const float4*)&Yb[(size_t)hrow * H_ + hcol];
        *(float4*)&bb.Ht[0][hrow + 16][hcol] =
            *(const float4*)&Yb[(size_t)(hrow + 16) * H_ + hcol];
        Lt[0][lk][lm] = L[(size_t)(m0 + lm) * N_ + lk];
    }
    __syncthreads();

    const int g = tid >> 6;
    const int l = tid & 63;
    const int ty = l >> 4;
    const int tx = l & 15;
    const int ma0 = ty * 4;
    const int ca0 = tx * 4, cb0 = 64 + tx * 4;

    float acc[4][2][4] = {};

    for (int kc = 0; kc < 16; ++kc) {
        const int bi = kc & 1, bj = bi ^ 1;
        float4 p0, p1;
        float pl;
        if (kc < 15) {
            const size_t kb = (size_t)(kc + 1) * 32;
            p0 = *(const float4*)&Yb[(kb + hrow) * H_ + hcol];
            p1 = *(const float4*)&Yb[(kb + hrow + 16) * H_ + hcol];
            pl = L[(size_t)(m0 + lm) * N_ + kb + lk];
        }
#pragma unroll
        for (int kk = 0; kk < 4; ++kk) {
            const int k = g * 4 + kk;
            const float4 la = *(const float4*)&Lt[bi][k][ma0];
            const float4 h0 = *(const float4*)&bb.Ht[bi][k][ca0];
            const float4 h1 = *(const float4*)&bb.Ht[bi][k][cb0];
            FMA4(acc[0][0], la.x, h0) FMA4(acc[0][1], la.x, h1)
            FMA4(acc[1][0], la.y, h0) FMA4(acc[1][1], la.y, h1)
            FMA4(acc[2][0], la.z, h0) FMA4(acc[2][1], la.z, h1)
            FMA4(acc[3][0], la.w, h0) FMA4(acc[3][1], la.w, h1)
        }
        if (kc < 15) {
            *(float4*)&bb.Ht[bj][hrow][hcol] = p0;
            *(float4*)&bb.Ht[bj][hrow + 16][hcol] = p1;
            Lt[bj][lk][lm] = pl;
        }
        __syncthreads();
    }

    for (int r = 0; r < 8; ++r) {
        if (g == r) {
#pragma unroll
            for (int i = 0; i < 4; ++i) {
#pragma unroll
                for (int v = 0; v < 2; ++v) {
                    const int c = v ? cb0 : ca0;
                    float4* zp = (float4*)&bb.s.Zb[ma0 + i][c];
                    if (r == 0) {
                        *zp = make_float4(acc[i][v][0], acc[i][v][1],
                                          acc[i][v][2], acc[i][v][3]);
                    } else {
                        float4 z = *zp;
                        *zp = make_float4(z.x + acc[i][v][0], z.y + acc[i][v][1],
                                          z.z + acc[i][v][2], z.w + acc[i][v][3]);
                    }
                }
            }
        }
        __syncthreads();
    }

    const int zr = tid >> 5;                       // 0..15
    const int zc = (tid & 31) * 4;                 // 0..124
    const float4 zv = *(const float4*)&bb.s.Zb[zr][zc];
    const float4 w0r = *(const float4*)&W2[zc];
    const float4 bbv = *(const float4*)&b2[zc];
    const float4 awv = *(const float4*)&aw1[zc];
    const float lx = Lx[((size_t)b * T_ + t) * N_ + m0 + zr];

    float c0 = tanhf(zv.x + lx * w0r.x + bbv.x);
    float c1 = tanhf(zv.y + lx * w0r.y + bbv.y);
    float c2 = tanhf(zv.z + lx * w0r.z + bbv.z);
    float c3 = tanhf(zv.w + lx * w0r.w + bbv.w);

    const size_t fl = (size_t)b * NH + (size_t)(m0 + zr) * H_ + zc;
    const float4 uv = *(const float4*)&u[fl];
    const float4 hp = *(const float4*)&Hprev[fl];
    const float h0 = uv.x * hp.x + (1.f - uv.x) * c0;
    const float h1 = uv.y * hp.y + (1.f - uv.y) * c1;
    const float h2 = uv.z * hp.z + (1.f - uv.z) * c2;
    const float h3 = uv.w * hp.w + (1.f - uv.w) * c3;
    *(float4*)&Hnew[fl] = make_float4(h0, h1, h2, h3);

    float part = h0 * awv.x + h1 * awv.y + h2 * awv.z + h3 * awv.w;
#pragma unroll
    for (int off = 16; off; off >>= 1) part += __shfl_xor(part, off);
    if ((tid & 31) == 0)
        hs1[((size_t)b * T_ + t) * N_ + m0 + zr] = part + ab1[0];
}

// ---------------------------------------------------------------------------
// beta[b,t] = softmax_t( (hs1@aw2+ab2) * (hs1@aw3+ab3) )
// ---------------------------------------------------------------------------
__global__ __launch_bounds__(64) void att_beta_kernel(
    const float* __restrict__ hs1, const float* __restrict__ aw2,
    const float* __restrict__ aw3, const float* __restrict__ ab2,
    const float* __restrict__ ab3, float* __restrict__ beta) {
    const int b = blockIdx.x;
    const int t = threadIdx.x;
    const float* __restrict__ row = hs1 + ((size_t)b * T_ + t) * N_;
    float f = 0.f, g = 0.f;
    for (int n = 0; n < N_; n += 4) {
        float4 hv = *(const float4*)&row[n];
        float4 w2v = *(const float4*)&aw2[n];
        float4 w3v = *(const float4*)&aw3[n];
        f += hv.x * w2v.x + hv.y * w2v.y + hv.z * w2v.z + hv.w * w2v.w;
        g += hv.x * w3v.x + hv.y * w3v.y + hv.z * w3v.z + hv.w * w3v.w;
    }
    f += ab2[0];
    g += ab3[0];
    float s = f * g;
    float mx = s;
    for (int off = 32; off; off >>= 1) mx = fmaxf(mx, __shfl_xor(mx, off));
    float e = expf(s - mx);
    float sum = e;
    for (int off = 32; off; off >>= 1) sum += __shfl_xor(sum, off);
    beta[b * T_ + t] = e / sum;
}

// ---------------------------------------------------------------------------
// out[b,p,n] = b_out[p] + sum_t beta[b,t]*hs1[b,t,n]*W_out[t,p]
// ---------------------------------------------------------------------------
__global__ __launch_bounds__(256) void att_out_kernel(
    const float* __restrict__ hs1, const float* __restrict__ beta,
    const float* __restrict__ Wout, const float* __restrict__ bout,
    float* __restrict__ out) {
    __shared__ float bs[T_];
    __shared__ float ws[T_][P_];
    const int b = blockIdx.x;
    const int tid = threadIdx.x;
    if (tid < T_) bs[tid] = beta[b * T_ + tid];
    for (int i = tid; i < T_ * P_; i += 256) ws[i / P_][i % P_] = Wout[i];
    __syncthreads();
    for (int nn = 0; nn < 2; ++nn) {
        const int n = tid + nn * 256;
        float acc[P_];
#pragma unroll
        for (int p = 0; p < P_; ++p) acc[p] = bout[p];
        for (int t = 0; t < T_; ++t) {
            float v = bs[t] * hs1[((size_t)b * T_ + t) * N_ + n];
#pragma unroll
            for (int p = 0; p < P_; ++p) acc[p] += v * ws[t][p];
        }
#pragma unroll
        for (int p = 0; p < P_; ++p) out[((size_t)b * P_ + p) * N_ + n] = acc[p];
    }
}

extern "C" void kernel_launch(void* const* d_in, const int* in_sizes, int n_in,
                              void* d_out, int out_size, void* d_ws, size_t ws_size,
                              hipStream_t stream) {
    const float* x = (const float*)d_in[0];
    const float* L = (const float*)d_in[1];
    const float* W1 = (const float*)d_in[2];
    const float* b1 = (const float*)d_in[3];
    const float* W2 = (const float*)d_in[4];
    const float* b2 = (const float*)d_in[5];
    const float* aw1 = (const float*)d_in[6];
    const float* aw2 = (const float*)d_in[7];
    const float* aw3 = (const float*)d_in[8];
    const float* ab1 = (const float*)d_in[9];
    const float* ab2 = (const float*)d_in[10];
    const float* ab3 = (const float*)d_in[11];
    const float* Wout = (const float*)d_in[12];
    const float* bout = (const float*)d_in[13];
    float* out = (float*)d_out;

    float* ws = (float*)d_ws;
    float* Lx = ws;                       // B*T*N
    float* hs1 = Lx + B_ * T_ * N_;       // B*T*N
    float* hb0 = hs1 + B_ * T_ * N_;      // B*N*H
    float* hb1 = hb0 + (size_t)B_ * NH;   // B*N*H
    float* u = hb1 + (size_t)B_ * NH;     // B*N*H
    float* Ybuf = u + (size_t)B_ * NH;    // B*N*H
    float* beta = Ybuf + (size_t)B_ * NH; // B*T
    (void)in_sizes; (void)n_in; (void)out_size; (void)ws_size;

    hipMemsetAsync(hb0, 0, (size_t)B_ * NH * sizeof(float), stream);
    lx_kernel<<<512, 512, 0, stream>>>(x, L, Lx);

    for (int t = 0; t < T_; ++t) {
        float* hp = (t & 1) ? hb1 : hb0;
        float* hn = (t & 1) ? hb0 : hb1;   // dead H(t-2): reused as Z, then Hnew
        gc1z_kernel<<<512, 512, 0, stream>>>(L, hp, hn);
        ruy_kernel<<<1024, 256, 0, stream>>>(hn, hp, Lx, W1, b1, W2, Ybuf, u, t);
        gcz_kernel<<<512, 512, 0, stream>>>(L, Ybuf, hp, u, Lx, W2, b2, aw1,
                                            ab1, hn, hs1, t);
    }
    att_beta_kernel<<<16, 64, 0, stream>>>(hs1, aw2, aw3, ab2, ab3, beta);
    att_out_kernel<<<16, 256, 0, stream>>>(hs1, beta, Wout, bout, out);
}

// Round 13
// 4171.305 us; speedup vs baseline: 1.3887x; 1.3887x over previous
//
#include <hip/hip_runtime.h>
#include <math.h>

#define B_ 16
#define T_ 64
#define N_ 512
#define H_ 128
#define P_ 12
#define NH 65536  // N_*H_

// ---------------------------------------------------------------------------
// Lx[b,t,m] = sum_n L[m,n] * x[b,t,n]   (L symmetric)
// ---------------------------------------------------------------------------
__global__ __launch_bounds__(512) void lx_kernel(const float* __restrict__ x,
                                                 const float* __restrict__ L,
                                                 float* __restrict__ Lx) {
    __shared__ __align__(16) float xs[2][N_];
    const int r0 = blockIdx.x * 2;
    const int tid = threadIdx.x;
    for (int j = 0; j < 2; ++j)
        xs[j][tid] = x[(size_t)(r0 + j) * N_ + tid];
    __syncthreads();
    float a0 = 0.f, a1 = 0.f;
    const int m = tid;
#pragma unroll 8
    for (int n = 0; n < N_; ++n) {
        float lv = L[(size_t)n * N_ + m];
        a0 += xs[0][n] * lv;
        a1 += xs[1][n] * lv;
    }
    Lx[(size_t)(r0 + 0) * N_ + m] = a0;
    Lx[(size_t)(r0 + 1) * N_ + m] = a1;
}

#define FMA4(dst, a, hv)                                                      \
    dst[0] += (a) * (hv).x; dst[1] += (a) * (hv).y;                           \
    dst[2] += (a) * (hv).z; dst[3] += (a) * (hv).w;

// ===========================================================================
// gc1z — R22 version verbatim (phase-1-only + Z dump).  (The 20ms rocprof
// row last round is a replay artifact — 64 such dispatches would exceed the
// 5.8ms total; timed arithmetic puts gc1z ~20us.)
// ===========================================================================
__global__ __launch_bounds__(512) void gc1z_kernel(
    const float* __restrict__ L, const float* __restrict__ Hprev,
    float* __restrict__ Z) {
    __shared__ __align__(16) float Ht[2][32][H_];   // 32768 B
    __shared__ __align__(16) float Lt[2][32][20];   // 5120 B
    __shared__ __align__(16) float Zb[16][H_];      // 8192 B

    const int tid = threadIdx.x;
    const int b = blockIdx.x & 15;
    const int m0 = (blockIdx.x >> 4) * 16;
    const float* __restrict__ Hb = Hprev + (size_t)b * NH;

    const int hrow = tid >> 5, hcol = (tid & 31) * 4;
    const int lm = tid >> 5, lk = tid & 31;

    {
        *(float4*)&Ht[0][hrow][hcol] = *(const float4*)&Hb[(size_t)hrow * H_ + hcol];
        *(float4*)&Ht[0][hrow + 16][hcol] =
            *(const float4*)&Hb[(size_t)(hrow + 16) * H_ + hcol];
        Lt[0][lk][lm] = L[(size_t)(m0 + lm) * N_ + lk];
    }
    __syncthreads();

    const int g = tid >> 6;
    const int l = tid & 63;
    const int ty = l >> 4;
    const int tx = l & 15;
    const int ma0 = ty * 4;
    const int ca0 = tx * 4, cb0 = 64 + tx * 4;

    float acc[4][2][4] = {};

    for (int kc = 0; kc < 16; ++kc) {
        const int bi = kc & 1, bj = bi ^ 1;
        float4 p0, p1;
        float pl;
        if (kc < 15) {
            const size_t kb = (size_t)(kc + 1) * 32;
            p0 = *(const float4*)&Hb[(kb + hrow) * H_ + hcol];
            p1 = *(const float4*)&Hb[(kb + hrow + 16) * H_ + hcol];
            pl = L[(size_t)(m0 + lm) * N_ + kb + lk];
        }
#pragma unroll
        for (int kk = 0; kk < 4; ++kk) {
            const int k = g * 4 + kk;
            const float4 la = *(const float4*)&Lt[bi][k][ma0];
            const float4 h0 = *(const float4*)&Ht[bi][k][ca0];
            const float4 h1 = *(const float4*)&Ht[bi][k][cb0];
            FMA4(acc[0][0], la.x, h0) FMA4(acc[0][1], la.x, h1)
            FMA4(acc[1][0], la.y, h0) FMA4(acc[1][1], la.y, h1)
            FMA4(acc[2][0], la.z, h0) FMA4(acc[2][1], la.z, h1)
            FMA4(acc[3][0], la.w, h0) FMA4(acc[3][1], la.w, h1)
        }
        if (kc < 15) {
            *(float4*)&Ht[bj][hrow][hcol] = p0;
            *(float4*)&Ht[bj][hrow + 16][hcol] = p1;
            Lt[bj][lk][lm] = pl;
        }
        __syncthreads();
    }

    for (int r = 0; r < 8; ++r) {
        if (g == r) {
#pragma unroll
            for (int i = 0; i < 4; ++i) {
#pragma unroll
                for (int v = 0; v < 2; ++v) {
                    const int c = v ? cb0 : ca0;
                    float4* zp = (float4*)&Zb[ma0 + i][c];
                    if (r == 0) {
                        *zp = make_float4(acc[i][v][0], acc[i][v][1],
                                          acc[i][v][2], acc[i][v][3]);
                    } else {
                        float4 z = *zp;
                        *zp = make_float4(z.x + acc[i][v][0], z.y + acc[i][v][1],
                                          z.z + acc[i][v][2], z.w + acc[i][v][3]);
                    }
                }
            }
        }
        __syncthreads();
    }

    {
        const int zr = tid >> 5, zc = (tid & 31) * 4;
        *(float4*)&Z[((size_t)b * NH) + (size_t)(m0 + zr) * H_ + zc] =
            *(const float4*)&Zb[zr][zc];
    }
}

// ===========================================================================
// ruy — R23: R22's structure with the bank-conflict bug FIXED.  R22 used
// o0=(tid&31)*8 (32B lane stride -> 8-way conflict, 14.45M counted, 56us).
// Now R13-gc2b's proven 16B-stride geometry everywhere: o0=(tid&31)*4;
// GEMM1 owns cols {o0, 128+o0}; Y phase owns rows {yr, yr+8} x cols o0,
// consuming 4 W-rows at a time (gc2b's exact inner-loop form, 0 conflicts).
// Tripwires: conflicts>1M = still wrong; dur>=25us = structure theory dead.
// ===========================================================================
__global__ __launch_bounds__(256) void ruy_kernel(
    const float* __restrict__ Z, const float* __restrict__ Hprev,
    const float* __restrict__ Lx, const float* __restrict__ W1,
    const float* __restrict__ b1, const float* __restrict__ W2,
    float* __restrict__ Y, float* __restrict__ u, int t) {
    __shared__ __align__(16) float Zs[8][H_];     //  4096 B
    __shared__ __align__(16) float Wt[16][256];   // 16384 B
    __shared__ __align__(16) float Rs[16][H_];    //  8192 B -> 28672 B

    const int tid = threadIdx.x;
    const int b = blockIdx.x & 15;                 // XCD-locality decode
    const int mt = blockIdx.x >> 4;                // 0..63
    const int m0 = mt * 8;
    const int row = tid >> 5;                      // 0..7
    const int n = m0 + row;                        // this thread's Z row
    const int o0 = (tid & 31) * 4;                 // 0..124 (16B stride)

    *(float4*)&Zs[row][o0] =
        *(const float4*)&Z[(size_t)b * NH + (size_t)n * H_ + o0];

    float v[2][4] = {};   // cols o0..o0+3 and 128+o0..128+o0+3
#pragma unroll 1
    for (int ck = 0; ck < 8; ++ck) {
        __syncthreads();   // ck=0: Zs visible; ck>0: protect Wt overwrite
        {   // stage W1 rows 1+16ck..16+16ck (4096 floats), flat conflict-free
            const float4* src = (const float4*)&W1[(size_t)(1 + ck * 16) * 256];
            float4* dst = (float4*)&Wt[0][0];
            dst[tid] = src[tid];
            dst[tid + 256] = src[tid + 256];
            dst[tid + 512] = src[tid + 512];
            dst[tid + 768] = src[tid + 768];
        }
        __syncthreads();
#pragma unroll
        for (int ch4 = 0; ch4 < 4; ++ch4) {
            const int cc = ck * 16 + ch4 * 4;
            const float4 zv = *(const float4*)&Zs[row][cc];   // broadcast
            const float4 wa0 = *(const float4*)&Wt[ch4 * 4 + 0][o0];
            const float4 wa1 = *(const float4*)&Wt[ch4 * 4 + 1][o0];
            const float4 wa2 = *(const float4*)&Wt[ch4 * 4 + 2][o0];
            const float4 wa3 = *(const float4*)&Wt[ch4 * 4 + 3][o0];
            v[0][0] += zv.x * wa0.x + zv.y * wa1.x + zv.z * wa2.x + zv.w * wa3.x;
            v[0][1] += zv.x * wa0.y + zv.y * wa1.y + zv.z * wa2.y + zv.w * wa3.y;
            v[0][2] += zv.x * wa0.z + zv.y * wa1.z + zv.z * wa2.z + zv.w * wa3.z;
            v[0][3] += zv.x * wa0.w + zv.y * wa1.w + zv.z * wa2.w + zv.w * wa3.w;
            const float4 wb0 = *(const float4*)&Wt[ch4 * 4 + 0][o0 + 128];
            const float4 wb1 = *(const float4*)&Wt[ch4 * 4 + 1][o0 + 128];
            const float4 wb2 = *(const float4*)&Wt[ch4 * 4 + 2][o0 + 128];
            const float4 wb3 = *(const float4*)&Wt[ch4 * 4 + 3][o0 + 128];
            v[1][0] += zv.x * wb0.x + zv.y * wb1.x + zv.z * wb2.x + zv.w * wb3.x;
            v[1][1] += zv.x * wb0.y + zv.y * wb1.y + zv.z * wb2.y + zv.w * wb3.y;
            v[1][2] += zv.x * wb0.z + zv.y * wb1.z + zv.z * wb2.z + zv.w * wb3.z;
            v[1][3] += zv.x * wb0.w + zv.y * wb1.w + zv.z * wb2.w + zv.w * wb3.w;
        }
    }
    __syncthreads();   // GEMM1 Wt reads done before Y-phase overwrite

    const float lx = Lx[((size_t)b * T_ + t) * N_ + n];
    float s0[4], s1[4];
#pragma unroll
    for (int j = 0; j < 4; ++j) {
        const float va = v[0][j] + lx * W1[o0 + j] + b1[o0 + j];
        s0[j] = 1.f / (1.f + expf(-va));
        const float vb = v[1][j] + lx * W1[128 + o0 + j] + b1[128 + o0 + j];
        s1[j] = 1.f / (1.f + expf(-vb));
    }

    if (mt < 32) {
        // r-half: Rs = s * Hprev.  flat n*256+o0 -> H row 2n, col o0;
        // flat n*256+128+o0 -> H row 2n+1, col o0.
        const float* __restrict__ Hb = Hprev + (size_t)b * NH;
        const int fl = n * 256 + o0;
        const float4 h0 = *(const float4*)&Hb[fl];
        const float4 h1 = *(const float4*)&Hb[fl + 128];
        *(float4*)&Rs[2 * row][o0] =
            make_float4(s0[0] * h0.x, s0[1] * h0.y, s0[2] * h0.z, s0[3] * h0.w);
        *(float4*)&Rs[2 * row + 1][o0] =
            make_float4(s1[0] * h1.x, s1[1] * h1.y, s1[2] * h1.z, s1[3] * h1.w);
        __syncthreads();

        // Y phase: Y rows 2m0..2m0+15 = Rs @ W2[1:]  (rows yr, yr+8; col o0)
        const int yr = tid >> 5;          // 0..7
        float a3[2][4] = {};
        float* __restrict__ W2t = &Wt[0][0];   // [16][128] pitch 128
#pragma unroll 1
        for (int ck = 0; ck < 8; ++ck) {
            {   // stage W2 rows 1+16ck..16+16ck (2048 floats), flat copy
                const float4* src = (const float4*)&W2[(size_t)(1 + ck * 16) * H_];
                float4* dst = (float4*)W2t;
                dst[tid] = src[tid];
                dst[tid + 256] = src[tid + 256];
            }
            __syncthreads();
#pragma unroll
            for (int ch4 = 0; ch4 < 4; ++ch4) {
                const int cc = ck * 16 + ch4 * 4;
                const float4 z0 = *(const float4*)&Rs[yr][cc];       // broadcast
                const float4 z1 = *(const float4*)&Rs[yr + 8][cc];   // broadcast
                const float4 w0 = *(const float4*)&W2t[(ch4 * 4 + 0) * 128 + o0];
                const float4 w1 = *(const float4*)&W2t[(ch4 * 4 + 1) * 128 + o0];
                const float4 w2 = *(const float4*)&W2t[(ch4 * 4 + 2) * 128 + o0];
                const float4 w3 = *(const float4*)&W2t[(ch4 * 4 + 3) * 128 + o0];
                a3[0][0] += z0.x * w0.x + z0.y * w1.x + z0.z * w2.x + z0.w * w3.x;
                a3[0][1] += z0.x * w0.y + z0.y * w1.y + z0.z * w2.y + z0.w * w3.y;
                a3[0][2] += z0.x * w0.z + z0.y * w1.z + z0.z * w2.z + z0.w * w3.z;
                a3[0][3] += z0.x * w0.w + z0.y * w1.w + z0.z * w2.w + z0.w * w3.w;
                a3[1][0] += z1.x * w0.x + z1.y * w1.x + z1.z * w2.x + z1.w * w3.x;
                a3[1][1] += z1.x * w0.y + z1.y * w1.y + z1.z * w2.y + z1.w * w3.y;
                a3[1][2] += z1.x * w0.z + z1.y * w1.z + z1.z * w2.z + z1.w * w3.z;
                a3[1][3] += z1.x * w0.w + z1.y * w1.w + z1.z * w2.w + z1.w * w3.w;
            }
            __syncthreads();
        }
        float* __restrict__ Yb = Y + (size_t)b * NH;
        *(float4*)&Yb[(size_t)(2 * m0 + yr) * H_ + o0] =
            make_float4(a3[0][0], a3[0][1], a3[0][2], a3[0][3]);
        *(float4*)&Yb[(size_t)(2 * m0 + yr + 8) * H_ + o0] =
            make_float4(a3[1][0], a3[1][1], a3[1][2], a3[1][3]);
    } else {
        // u-half: flat (n-256)*256+o0 == H-layout linear
        float* __restrict__ uB = u + (size_t)b * NH;
        const int fl = (n - 256) * 256 + o0;
        *(float4*)&uB[fl] = make_float4(s0[0], s0[1], s0[2], s0[3]);
        *(float4*)&uB[fl + 128] = make_float4(s1[0], s1[1], s1[2], s1[3]);
    }
}

// ===========================================================================
// gcz_kernel — R18 version VERBATIM (passed, ~13us): (L@Y) + gate epilogue.
// LDS 37,888 B.  DO NOT PERTURB.
// ===========================================================================
__global__ __launch_bounds__(512) void gcz_kernel(
    const float* __restrict__ L, const float* __restrict__ Y,
    const float* __restrict__ Hprev, const float* __restrict__ u,
    const float* __restrict__ Lx, const float* __restrict__ W2,
    const float* __restrict__ b2, const float* __restrict__ aw1,
    const float* __restrict__ ab1, float* __restrict__ Hnew,
    float* __restrict__ hs1, int t) {
    __shared__ __align__(16) union Buf {
        float Ht[2][32][H_];                              // 32768 B
        struct { float R[32][H_]; float Zb[16][H_]; } s;  // R unused here
    } bb;
    __shared__ __align__(16) float Lt[2][32][20];         // 5120 B

    const int tid = threadIdx.x;
    const int b = blockIdx.x & 15;
    const int m0 = (blockIdx.x >> 4) * 16;
    const float* __restrict__ Yb = Y + (size_t)b * NH;

    const int hrow = tid >> 5, hcol = (tid & 31) * 4;
    const int lm = tid >> 5, lk = tid & 31;

    {
        *(float4*)&bb.Ht[0][hrow][hcol] =
            *(const float4*)&Yb[(size_t)hrow * H_ + hcol];
        *(float4*)&bb.Ht[0][hrow + 16][hcol] =
            *(const float4*)&Yb[(size_t)(hrow + 16) * H_ + hcol];
        Lt[0][lk][lm] = L[(size_t)(m0 + lm) * N_ + lk];
    }
    __syncthreads();

    const int g = tid >> 6;
    const int l = tid & 63;
    const int ty = l >> 4;
    const int tx = l & 15;
    const int ma0 = ty * 4;
    const int ca0 = tx * 4, cb0 = 64 + tx * 4;

    float acc[4][2][4] = {};

    for (int kc = 0; kc < 16; ++kc) {
        const int bi = kc & 1, bj = bi ^ 1;
        float4 p0, p1;
        float pl;
        if (kc < 15) {
            const size_t kb = (size_t)(kc + 1) * 32;
            p0 = *(const float4*)&Yb[(kb + hrow) * H_ + hcol];
            p1 = *(const float4*)&Yb[(kb + hrow + 16) * H_ + hcol];
            pl = L[(size_t)(m0 + lm) * N_ + kb + lk];
        }
#pragma unroll
        for (int kk = 0; kk < 4; ++kk) {
            const int k = g * 4 + kk;
            const float4 la = *(const float4*)&Lt[bi][k][ma0];
            const float4 h0 = *(const float4*)&bb.Ht[bi][k][ca0];
            const float4 h1 = *(const float4*)&bb.Ht[bi][k][cb0];
            FMA4(acc[0][0], la.x, h0) FMA4(acc[0][1], la.x, h1)
            FMA4(acc[1][0], la.y, h0) FMA4(acc[1][1], la.y, h1)
            FMA4(acc[2][0], la.z, h0) FMA4(acc[2][1], la.z, h1)
            FMA4(acc[3][0], la.w, h0) FMA4(acc[3][1], la.w, h1)
        }
        if (kc < 15) {
            *(float4*)&bb.Ht[bj][hrow][hcol] = p0;
            *(float4*)&bb.Ht[bj][hrow + 16][hcol] = p1;
            Lt[bj][lk][lm] = pl;
        }
        __syncthreads();
    }

    for (int r = 0; r < 8; ++r) {
        if (g == r) {
#pragma unroll
            for (int i = 0; i < 4; ++i) {
#pragma unroll
                for (int v = 0; v < 2; ++v) {
                    const int c = v ? cb0 : ca0;
                    float4* zp = (float4*)&bb.s.Zb[ma0 + i][c];
                    if (r == 0) {
                        *zp = make_float4(acc[i][v][0], acc[i][v][1],
                                          acc[i][v][2], acc[i][v][3]);
                    } else {
                        float4 z = *zp;
                        *zp = make_float4(z.x + acc[i][v][0], z.y + acc[i][v][1],
                                          z.z + acc[i][v][2], z.w + acc[i][v][3]);
                    }
                }
            }
        }
        __syncthreads();
    }

    const int zr = tid >> 5;                       // 0..15
    const int zc = (tid & 31) * 4;                 // 0..124
    const float4 zv = *(const float4*)&bb.s.Zb[zr][zc];
    const float4 w0r = *(const float4*)&W2[zc];
    const float4 bbv = *(const float4*)&b2[zc];
    const float4 awv = *(const float4*)&aw1[zc];
    const float lx = Lx[((size_t)b * T_ + t) * N_ + m0 + zr];

    float c0 = tanhf(zv.x + lx * w0r.x + bbv.x);
    float c1 = tanhf(zv.y + lx * w0r.y + bbv.y);
    float c2 = tanhf(zv.z + lx * w0r.z + bbv.z);
    float c3 = tanhf(zv.w + lx * w0r.w + bbv.w);

    const size_t fl = (size_t)b * NH + (size_t)(m0 + zr) * H_ + zc;
    const float4 uv = *(const float4*)&u[fl];
    const float4 hp = *(const float4*)&Hprev[fl];
    const float h0 = uv.x * hp.x + (1.f - uv.x) * c0;
    const float h1 = uv.y * hp.y + (1.f - uv.y) * c1;
    const float h2 = uv.z * hp.z + (1.f - uv.z) * c2;
    const float h3 = uv.w * hp.w + (1.f - uv.w) * c3;
    *(float4*)&Hnew[fl] = make_float4(h0, h1, h2, h3);

    float part = h0 * awv.x + h1 * awv.y + h2 * awv.z + h3 * awv.w;
#pragma unroll
    for (int off = 16; off; off >>= 1) part += __shfl_xor(part, off);
    if ((tid & 31) == 0)
        hs1[((size_t)b * T_ + t) * N_ + m0 + zr] = part + ab1[0];
}

// ---------------------------------------------------------------------------
// beta[b,t] = softmax_t( (hs1@aw2+ab2) * (hs1@aw3+ab3) )
// ---------------------------------------------------------------------------
__global__ __launch_bounds__(64) void att_beta_kernel(
    const float* __restrict__ hs1, const float* __restrict__ aw2,
    const float* __restrict__ aw3, const float* __restrict__ ab2,
    const float* __restrict__ ab3, float* __restrict__ beta) {
    const int b = blockIdx.x;
    const int t = threadIdx.x;
    const float* __restrict__ row = hs1 + ((size_t)b * T_ + t) * N_;
    float f = 0.f, g = 0.f;
    for (int n = 0; n < N_; n += 4) {
        float4 hv = *(const float4*)&row[n];
        float4 w2v = *(const float4*)&aw2[n];
        float4 w3v = *(const float4*)&aw3[n];
        f += hv.x * w2v.x + hv.y * w2v.y + hv.z * w2v.z + hv.w * w2v.w;
        g += hv.x * w3v.x + hv.y * w3v.y + hv.z * w3v.z + hv.w * w3v.w;
    }
    f += ab2[0];
    g += ab3[0];
    float s = f * g;
    float mx = s;
    for (int off = 32; off; off >>= 1) mx = fmaxf(mx, __shfl_xor(mx, off));
    float e = expf(s - mx);
    float sum = e;
    for (int off = 32; off; off >>= 1) sum += __shfl_xor(sum, off);
    beta[b * T_ + t] = e / sum;
}

// ---------------------------------------------------------------------------
// out[b,p,n] = b_out[p] + sum_t beta[b,t]*hs1[b,t,n]*W_out[t,p]
// ---------------------------------------------------------------------------
__global__ __launch_bounds__(256) void att_out_kernel(
    const float* __restrict__ hs1, const float* __restrict__ beta,
    const float* __restrict__ Wout, const float* __restrict__ bout,
    float* __restrict__ out) {
    __shared__ float bs[T_];
    __shared__ float ws[T_][P_];
    const int b = blockIdx.x;
    const int tid = threadIdx.x;
    if (tid < T_) bs[tid] = beta[b * T_ + tid];
    for (int i = tid; i < T_ * P_; i += 256) ws[i / P_][i % P_] = Wout[i];
    __syncthreads();
    for (int nn = 0; nn < 2; ++nn) {
        const int n = tid + nn * 256;
        float acc[P_];
#pragma unroll
        for (int p = 0; p < P_; ++p) acc[p] = bout[p];
        for (int t = 0; t < T_; ++t) {
            float v = bs[t] * hs1[((size_t)b * T_ + t) * N_ + n];
#pragma unroll
            for (int p = 0; p < P_; ++p) acc[p] += v * ws[t][p];
        }
#pragma unroll
        for (int p = 0; p < P_; ++p) out[((size_t)b * P_ + p) * N_ + n] = acc[p];
    }
}

extern "C" void kernel_launch(void* const* d_in, const int* in_sizes, int n_in,
                              void* d_out, int out_size, void* d_ws, size_t ws_size,
                              hipStream_t stream) {
    const float* x = (const float*)d_in[0];
    const float* L = (const float*)d_in[1];
    const float* W1 = (const float*)d_in[2];
    const float* b1 = (const float*)d_in[3];
    const float* W2 = (const float*)d_in[4];
    const float* b2 = (const float*)d_in[5];
    const float* aw1 = (const float*)d_in[6];
    const float* aw2 = (const float*)d_in[7];
    const float* aw3 = (const float*)d_in[8];
    const float* ab1 = (const float*)d_in[9];
    const float* ab2 = (const float*)d_in[10];
    const float* ab3 = (const float*)d_in[11];
    const float* Wout = (const float*)d_in[12];
    const float* bout = (const float*)d_in[13];
    float* out = (float*)d_out;

    float* ws = (float*)d_ws;
    float* Lx = ws;                       // B*T*N
    float* hs1 = Lx + B_ * T_ * N_;       // B*T*N
    float* hb0 = hs1 + B_ * T_ * N_;      // B*N*H
    float* hb1 = hb0 + (size_t)B_ * NH;   // B*N*H
    float* u = hb1 + (size_t)B_ * NH;     // B*N*H
    float* Ybuf = u + (size_t)B_ * NH;    // B*N*H
    float* beta = Ybuf + (size_t)B_ * NH; // B*T
    (void)in_sizes; (void)n_in; (void)out_size; (void)ws_size;

    hipMemsetAsync(hb0, 0, (size_t)B_ * NH * sizeof(float), stream);
    lx_kernel<<<512, 512, 0, stream>>>(x, L, Lx);

    for (int t = 0; t < T_; ++t) {
        float* hp = (t & 1) ? hb1 : hb0;
        float* hn = (t & 1) ? hb0 : hb1;   // dead H(t-2): reused as Z, then Hnew
        gc1z_kernel<<<512, 512, 0, stream>>>(L, hp, hn);
        ruy_kernel<<<1024, 256, 0, stream>>>(hn, hp, Lx, W1, b1, W2, Ybuf, u, t);
        gcz_kernel<<<512, 512, 0, stream>>>(L, Ybuf, hp, u, Lx, W2, b2, aw1,
                                            ab1, hn, hs1, t);
    }
    att_beta_kernel<<<16, 64, 0, stream>>>(hs1, aw2, aw3, ab2, ab3, beta);
    att_out_kernel<<<16, 256, 0, stream>>>(hs1, beta, Wout, bout, out);
}